// Round 4
// baseline (743.100 us; speedup 1.0000x reference)
//
#include <hip/hip_runtime.h>

#define NN 2304
#define CC 256
#define HH 8
#define HD 32
#define NYY 48
#define SCALE 0.17677669529663687f
#define SPLITS 8
#define GRID 1536

typedef __bf16 bf16_t;
typedef __bf16 bf8v __attribute__((ext_vector_type(8)));
typedef float f4v __attribute__((ext_vector_type(4)));

__device__ __forceinline__ f4v mfma16(bf8v a, bf8v b, f4v c) {
    return __builtin_amdgcn_mfma_f32_16x16x32_bf16(a, b, c, 0, 0, 0);
}

// Replay-safe grid barrier (counter zeroed by hipMemsetAsync each launch).
// Spin with RELAXED agent loads; ONE acquire load on exit (L1/L2 inv) pulls
// peer-XCD data; arrival add carries RELEASE (L2 writeback). All GRID blocks
// co-resident: GRID=1536 = 6 blocks/CU at __launch_bounds__(256,6)
// (VGPR cap 85 >= 68 used, LDS 6*8.7KB=52KB <= 160KB).
__device__ __forceinline__ void gbar(int* cnt, int target) {
    __syncthreads();
    if (threadIdx.x == 0) {
        __hip_atomic_fetch_add(cnt, 1, __ATOMIC_RELEASE, __HIP_MEMORY_SCOPE_AGENT);
        while (__hip_atomic_load(cnt, __ATOMIC_RELAXED, __HIP_MEMORY_SCOPE_AGENT) < target) {
            __builtin_amdgcn_s_sleep(8);
        }
        (void)__hip_atomic_load(cnt, __ATOMIC_ACQUIRE, __HIP_MEMORY_SCOPE_AGENT);
    }
    __syncthreads();
}

// ---------------------------------------------------------------------------
// Single fused kernel, 5 phases separated by software grid barriers:
//   A: transpose x -> xT bf16; convert Wq|Wk|Wv|Wp -> Wb bf16   (416 units)
//   B: QKV projection GEMMs -> Qt (scaled), Kt, Vd              (864 units)
//   C: split-K attention -> pO, pl partials                     (288*SPLITS)
//   D: combine partials -> Yt bf16                              (2304 units)
//   E: output projection -> out fp32                            (288 units)
// ---------------------------------------------------------------------------
__global__ __launch_bounds__(256, 6) void k_fused(
    const float* __restrict__ x,
    const float* __restrict__ Wq, const float* __restrict__ bq,
    const float* __restrict__ Wk, const float* __restrict__ bk,
    const float* __restrict__ Wv, const float* __restrict__ bv,
    const float* __restrict__ Wp, const float* __restrict__ bp,
    const float* __restrict__ emb,
    bf16_t* __restrict__ xT, bf16_t* __restrict__ Qt, bf16_t* __restrict__ Kt,
    bf16_t* __restrict__ Vd, bf16_t* __restrict__ Yt, bf16_t* __restrict__ Wb,
    float* __restrict__ pO, float* __restrict__ pl, float* __restrict__ out,
    int* __restrict__ bar)
{
    const int t = threadIdx.x;
    const int wave = t >> 6, lane = t & 63;
    const int l15 = lane & 15, quad = lane >> 4;
    __shared__ float smem[2112];   // 8448 B: phase A tile[64][33]; phase C emb+p

    // ---------------- Phase A: preprocessing ----------------
    {
        const int b = blockIdx.x;
        if (b < 288) {
            float (*tile)[33] = (float (*)[33])smem;
            const int c0 = (b & 7) * 32;
            const int n0 = (b >> 3) * 64;
            const int n = t & 63, cb = t >> 6;
#pragma unroll
            for (int cc = 0; cc < 8; cc++) {
                int c = cc * 4 + cb;
                tile[n][c] = x[(size_t)(c0 + c) * NN + n0 + n];
            }
            __syncthreads();
            const int c2 = t & 31, nb2 = t >> 5;
#pragma unroll
            for (int nn = 0; nn < 8; nn++) {
                int n2 = nn * 8 + nb2;
                xT[(size_t)(n0 + n2) * CC + c0 + c2] = (bf16_t)tile[n2][c2];
            }
        } else if (b < 416) {
            const int wb = b - 288;
            const int matid = wb >> 5;
            const float* src = (matid == 0) ? Wq : (matid == 1) ? Wk : (matid == 2) ? Wv : Wp;
            const int base = (wb & 31) * 2048 + t * 8;
            float4 a = *(const float4*)(src + base);
            float4 c = *(const float4*)(src + base + 4);
            bf8v o;
            o[0] = (bf16_t)a.x; o[1] = (bf16_t)a.y; o[2] = (bf16_t)a.z; o[3] = (bf16_t)a.w;
            o[4] = (bf16_t)c.x; o[5] = (bf16_t)c.y; o[6] = (bf16_t)c.z; o[7] = (bf16_t)c.w;
            *(bf8v*)(Wb + (size_t)matid * 65536 + base) = o;
        }
    }
    gbar(bar, 1 * GRID);

    // ---------------- Phase B: QKV projection ----------------
    for (int u = blockIdx.x; u < 864; u += GRID) {
        const int nb = u % 72;
        const int rest = u / 72;
        const int ob = rest & 3;
        const int mat = rest >> 2;
        const bf16_t* W = Wb + (size_t)mat * 65536;
        const float* bias = (mat == 0) ? bq : (mat == 1) ? bk : bv;
        const int n0 = nb * 32;
        const int orow = ob * 64 + wave * 16;

        f4v acc0 = {0.f, 0.f, 0.f, 0.f}, acc1 = {0.f, 0.f, 0.f, 0.f};
#pragma unroll
        for (int k0 = 0; k0 < CC; k0 += 32) {
            bf8v af = *(const bf8v*)(W + (size_t)(orow + l15) * CC + k0 + quad * 8);
            bf8v b0 = *(const bf8v*)(xT + (size_t)(n0 + l15) * CC + k0 + quad * 8);
            bf8v b1 = *(const bf8v*)(xT + (size_t)(n0 + 16 + l15) * CC + k0 + quad * 8);
            acc0 = mfma16(af, b0, acc0);
            acc1 = mfma16(af, b1, acc1);
        }
#pragma unroll
        for (int r = 0; r < 4; r++) {
            const int o = orow + quad * 4 + r;
            const float bo = bias[o];
#pragma unroll
            for (int nb2 = 0; nb2 < 2; nb2++) {
                const int n = n0 + nb2 * 16 + l15;
                float v = (nb2 ? acc1[r] : acc0[r]) + bo;
                if (mat == 2) {
                    Vd[(size_t)o * NN + n] = (bf16_t)v;
                } else {
                    int h = o >> 5, d = o & 31;
                    bf16_t* dst = (mat == 0) ? Qt : Kt;
                    float vv = (mat == 0) ? v * SCALE : v;
                    dst[(size_t)h * NN * HD + (size_t)n * HD + d] = (bf16_t)vv;
                }
            }
        }
    }
    gbar(bar, 2 * GRID);

    // ---------------- Phase C: split-K attention ----------------
    {
        float* lds_emb = smem;
        bf16_t* plds = (bf16_t*)(smem + 64) + wave * 512;
        const int L = NN / SPLITS;
        const f4v z = {0.f, 0.f, 0.f, 0.f};
        for (int u = blockIdx.x; u < 288 * SPLITS; u += GRID) {
            const int bx = u % 288;
            const int sidx = u / 288;
            const int h = bx & 7;
            const int qt = bx >> 3;
            __syncthreads();   // prior unit's lds_emb readers done
            if (t < 37) lds_emb[t] = (t < 36) ? emb[t * HH + h] : 0.0f;
            __syncthreads();

            const int qg0 = qt * 64 + wave * 16;
            const bf16_t* Qh = Qt + (size_t)h * NN * HD;
            const bf16_t* Kh = Kt + (size_t)h * NN * HD;
            const bf16_t* Vh = Vd + (size_t)h * HD * NN;
            const bf8v aq = *(const bf8v*)(Qh + (size_t)(qg0 + l15) * HD + quad * 8);

            int xi[4], yi[4];
#pragma unroll
            for (int r = 0; r < 4; r++) {
                int qi = qg0 + quad * 4 + r;
                xi[r] = qi / NYY;
                yi[r] = qi - xi[r] * NYY;
            }
            const int xi_lo = qg0 / NYY;            // wave-uniform
            const int xi_hi = (qg0 + 15) / NYY;

            f4v o0 = z, o1 = z;
            float lsum[4] = {0.f, 0.f, 0.f, 0.f};

            const int k_begin = sidx * L, k_end = k_begin + L;
            for (int kb = k_begin; kb < k_end; kb += 32) {
                bf8v kf0 = *(const bf8v*)(Kh + (size_t)(kb + l15) * HD + quad * 8);
                bf8v kf1 = *(const bf8v*)(Kh + (size_t)(kb + 16 + l15) * HD + quad * 8);
                bf8v vf0 = *(const bf8v*)(Vh + (size_t)l15 * NN + kb + quad * 8);
                bf8v vf1 = *(const bf8v*)(Vh + (size_t)(16 + l15) * NN + kb + quad * 8);
                f4v s0 = mfma16(aq, kf0, z);
                f4v s1 = mfma16(aq, kf1, z);

                // Bias is 0 whenever |dx|>5: skip token math for chunks whose
                // whole x-range is out of window (wave-uniform branch, ~75%).
                const int xj_lo = kb / NYY;
                const int xj_hi = (kb + 31) / NYY;
                if (xj_lo > xi_hi + 5 || xj_hi + 5 < xi_lo) {
#pragma unroll
                    for (int cb = 0; cb < 2; cb++) {
                        const f4v& s = cb ? s1 : s0;
#pragma unroll
                        for (int r = 0; r < 4; r++) {
                            float p = __expf(s[r]);
                            lsum[r] += p;
                            plds[(quad * 4 + r) * 32 + cb * 16 + l15] = (bf16_t)p;
                        }
                    }
                } else {
#pragma unroll
                    for (int cb = 0; cb < 2; cb++) {
                        const f4v& s = cb ? s1 : s0;
                        int kj = kb + cb * 16 + l15;
                        int xj = kj / NYY;
                        int yj = kj - xj * NYY;
#pragma unroll
                        for (int r = 0; r < 4; r++) {
                            int dx = xi[r] - xj; dx = dx < 0 ? -dx : dx;
                            int dy = yi[r] - yj; dy = dy < 0 ? -dy : dy;
                            int tok = (dx > 5 || dy > 5) ? 36 : dx * 6 + dy;
                            float p = __expf(s[r] + lds_emb[tok]);
                            lsum[r] += p;
                            plds[(quad * 4 + r) * 32 + cb * 16 + l15] = (bf16_t)p;
                        }
                    }
                }
                bf8v ap = *(const bf8v*)(plds + l15 * 32 + quad * 8);
                o0 = mfma16(ap, vf0, o0);
                o1 = mfma16(ap, vf1, o1);
            }

            float* pO_s = pO + ((size_t)sidx * HH + h) * NN * HD;
            float* pl_s = pl + ((size_t)sidx * HH + h) * NN;
#pragma unroll
            for (int r = 0; r < 4; r++) {
                float v = lsum[r];
#pragma unroll
                for (int m = 1; m < 16; m <<= 1) v += __shfl_xor(v, m, 64);
                int row = qg0 + quad * 4 + r;
                pO_s[(size_t)row * HD + l15] = o0[r];
                pO_s[(size_t)row * HD + 16 + l15] = o1[r];
                if (l15 == 0) pl_s[row] = v;
            }
        }
    }
    gbar(bar, 3 * GRID);

    // ---------------- Phase D: combine partials -> Yt ----------------
    for (int u = blockIdx.x; u < (HH * NN * HD) / 256; u += GRID) {
        const int e = u * 256 + t;
        const int h = e / (NN * HD);
        const int rem = e - h * (NN * HD);
        const int q = rem >> 5;
        const int d = rem & 31;
        float so = 0.f, sl = 0.f;
#pragma unroll
        for (int s = 0; s < SPLITS; s++) {
            so += pO[((size_t)s * HH + h) * NN * HD + (size_t)q * HD + d];
            sl += pl[((size_t)s * HH + h) * NN + q];
        }
        Yt[(size_t)q * CC + h * HD + d] = (bf16_t)(so / sl);
    }
    gbar(bar, 4 * GRID);

    // ---------------- Phase E: output projection ----------------
    for (int u = blockIdx.x; u < 288; u += GRID) {
        const int n0 = (u % 72) * 32;
        const int orow = (u / 72) * 64 + wave * 16;
        const bf16_t* W = Wb + (size_t)3 * 65536;

        f4v acc0 = {0.f, 0.f, 0.f, 0.f}, acc1 = {0.f, 0.f, 0.f, 0.f};
#pragma unroll
        for (int k0 = 0; k0 < CC; k0 += 32) {
            bf8v af = *(const bf8v*)(W + (size_t)(orow + l15) * CC + k0 + quad * 8);
            bf8v b0 = *(const bf8v*)(Yt + (size_t)(n0 + l15) * CC + k0 + quad * 8);
            bf8v b1 = *(const bf8v*)(Yt + (size_t)(n0 + 16 + l15) * CC + k0 + quad * 8);
            acc0 = mfma16(af, b0, acc0);
            acc1 = mfma16(af, b1, acc1);
        }
#pragma unroll
        for (int r = 0; r < 4; r++) {
            const int o = orow + quad * 4 + r;
            const float bo = bp[o];
            out[(size_t)o * NN + n0 + l15] = acc0[r] + bo;
            out[(size_t)o * NN + n0 + 16 + l15] = acc1[r] + bo;
        }
    }
}

// ---------------------------------------------------------------------------
extern "C" void kernel_launch(void* const* d_in, const int* in_sizes, int n_in,
                              void* d_out, int out_size, void* d_ws, size_t ws_size,
                              hipStream_t stream) {
    const float* x   = (const float*)d_in[0];
    const float* Wq  = (const float*)d_in[1];
    const float* bq  = (const float*)d_in[2];
    const float* Wk  = (const float*)d_in[3];
    const float* bk  = (const float*)d_in[4];
    const float* Wv  = (const float*)d_in[5];
    const float* bv  = (const float*)d_in[6];
    const float* Wp  = (const float*)d_in[7];
    const float* bp  = (const float*)d_in[8];
    const float* emb = (const float*)d_in[9];
    // d_in[10] = tokens: recomputed analytically in-kernel, never read.
    float* out = (float*)d_out;

    bf16_t* xT = (bf16_t*)d_ws;              // NN*CC bf16
    bf16_t* Qt = xT + (size_t)NN * CC;       // (H, N, 32)
    bf16_t* Kt = Qt + (size_t)NN * CC;       // (H, N, 32)
    bf16_t* Vd = Kt + (size_t)NN * CC;       // (H, 32, N)
    bf16_t* Yt = Vd + (size_t)NN * CC;       // (N, 256)
    bf16_t* Wb = Yt + (size_t)NN * CC;       // 4 * 256*256 bf16
    float*  pO = (float*)(Wb + (size_t)4 * CC * CC);  // SPLITS*H*N*32 fp32
    float*  pl = pO + (size_t)SPLITS * HH * NN * HD;  // SPLITS*H*N fp32
    // barrier counter: 64B region after pl, 256B-aligned
    size_t bar_off = ((size_t)((char*)(pl + (size_t)SPLITS * HH * NN) - (char*)d_ws) + 255) & ~(size_t)255;
    int* bar = (int*)((char*)d_ws + bar_off);

    hipMemsetAsync(bar, 0, 64, stream);
    hipLaunchKernelGGL(k_fused, dim3(GRID), dim3(256), 0, stream,
                       x, Wq, bq, Wk, bk, Wv, bv, Wp, bp, emb,
                       xT, Qt, Kt, Vd, Yt, Wb, pO, pl, out, bar);
}

// Round 5
// 141.913 us; speedup vs baseline: 5.2363x; 5.2363x over previous
//
#include <hip/hip_runtime.h>

#define NN 2304
#define CC 256
#define HH 8
#define HD 32
#define NYY 48
#define SCALE 0.17677669529663687f

typedef __bf16 bf16_t;
typedef __bf16 bf8v __attribute__((ext_vector_type(8)));
typedef float f4v __attribute__((ext_vector_type(4)));

__device__ __forceinline__ f4v mfma16(bf8v a, bf8v b, f4v c) {
    return __builtin_amdgcn_mfma_f32_16x16x32_bf16(a, b, c, 0, 0, 0);
}

// ---------------------------------------------------------------------------
// Kernel 1 (fused preprocessing):
//   blocks [0,288):   transpose-convert x (256 x 2304 f32) -> xT (2304 x 256 bf16)
//   blocks [288,416): convert Wq|Wk|Wv|Wp (each 256x256 f32) -> Wb bf16 (4x65536)
// ---------------------------------------------------------------------------
__global__ __launch_bounds__(256) void k_pre(
    const float* __restrict__ x, bf16_t* __restrict__ xT,
    const float* __restrict__ Wq, const float* __restrict__ Wk,
    const float* __restrict__ Wv, const float* __restrict__ Wp,
    bf16_t* __restrict__ Wb) {
    const int b = blockIdx.x;
    const int t = threadIdx.x;
    if (b < 288) {
        __shared__ float tile[64][33];
        const int c0 = (b & 7) * 32;
        const int n0 = (b >> 3) * 64;
        const int n = t & 63, cb = t >> 6;
#pragma unroll
        for (int cc = 0; cc < 8; cc++) {
            int c = cc * 4 + cb;
            tile[n][c] = x[(size_t)(c0 + c) * NN + n0 + n];
        }
        __syncthreads();
        const int c = t & 31, nb = t >> 5;
#pragma unroll
        for (int nn = 0; nn < 8; nn++) {
            int n2 = nn * 8 + nb;
            xT[(size_t)(n0 + n2) * CC + c0 + c] = (bf16_t)tile[n2][c];
        }
    } else {
        const int wb = b - 288;
        const int matid = wb >> 5;            // 0..3
        const float* src = (matid == 0) ? Wq : (matid == 1) ? Wk : (matid == 2) ? Wv : Wp;
        const int base = (wb & 31) * 2048 + t * 8;
        float4 a = *(const float4*)(src + base);
        float4 c = *(const float4*)(src + base + 4);
        bf8v o;
        o[0] = (bf16_t)a.x; o[1] = (bf16_t)a.y; o[2] = (bf16_t)a.z; o[3] = (bf16_t)a.w;
        o[4] = (bf16_t)c.x; o[5] = (bf16_t)c.y; o[6] = (bf16_t)c.z; o[7] = (bf16_t)c.w;
        *(bf8v*)(Wb + (size_t)matid * 65536 + base) = o;
    }
}

// ---------------------------------------------------------------------------
// Kernel 2: QKV projection GEMM (M=256 o, N=2304 n, K=256 c), bf16 weights.
// Block: 64 o x 32 n (4 waves, each 16o x 32n, 2 accumulators).
//   Q -> Qt (H, N, 32) pre-scaled; K -> Kt (H, N, 32); V -> Vd (H, 32, N)
// ---------------------------------------------------------------------------
__global__ __launch_bounds__(256) void k_proj_qkv(
    const bf16_t* __restrict__ Wb,
    const float* __restrict__ bq, const float* __restrict__ bk,
    const float* __restrict__ bv,
    const bf16_t* __restrict__ xT,
    bf16_t* __restrict__ Qt, bf16_t* __restrict__ Kt, bf16_t* __restrict__ Vd) {
    const int mat = blockIdx.z;
    const bf16_t* W = Wb + (size_t)mat * 65536;
    const float* bias = (mat == 0) ? bq : (mat == 1) ? bk : bv;
    const int n0 = blockIdx.x * 32;
    const int o0 = blockIdx.y * 64;
    const int lane = threadIdx.x & 63;
    const int wave = threadIdx.x >> 6;
    const int l15 = lane & 15;
    const int quad = lane >> 4;
    const int orow = o0 + wave * 16;

    f4v acc0 = {0.f, 0.f, 0.f, 0.f}, acc1 = {0.f, 0.f, 0.f, 0.f};
#pragma unroll
    for (int k0 = 0; k0 < CC; k0 += 32) {
        bf8v af = *(const bf8v*)(W + (size_t)(orow + l15) * CC + k0 + quad * 8);
        bf8v b0 = *(const bf8v*)(xT + (size_t)(n0 + l15) * CC + k0 + quad * 8);
        bf8v b1 = *(const bf8v*)(xT + (size_t)(n0 + 16 + l15) * CC + k0 + quad * 8);
        acc0 = mfma16(af, b0, acc0);
        acc1 = mfma16(af, b1, acc1);
    }

#pragma unroll
    for (int r = 0; r < 4; r++) {
        const int o = orow + quad * 4 + r;
        const float bo = bias[o];
#pragma unroll
        for (int nb = 0; nb < 2; nb++) {
            const int n = n0 + nb * 16 + l15;
            float v = (nb ? acc1[r] : acc0[r]) + bo;
            if (mat == 2) {
                Vd[(size_t)o * NN + n] = (bf16_t)v;
            } else {
                int h = o >> 5, d = o & 31;
                bf16_t* dst = (mat == 0) ? Qt : Kt;
                float vv = (mat == 0) ? v * SCALE : v;
                dst[(size_t)h * NN * HD + (size_t)n * HD + d] = (bf16_t)vv;
            }
        }
    }
}

// ---------------------------------------------------------------------------
// Kernel 3: fused attention, split-K INSIDE the block (no pO/pl round-trip).
// Grid 1152 = 8 heads x 144 q-tiles of 16 rows. All 4 waves share the same
// 16 q-rows; wave w handles keys [w*576, (w+1)*576). Partials combined in
// LDS, normalized, written directly to Yt (N x 256) bf16.
// ---------------------------------------------------------------------------
__global__ __launch_bounds__(256, 4) void k_attn(
    const bf16_t* __restrict__ Qt, const bf16_t* __restrict__ Kt,
    const bf16_t* __restrict__ Vd, const float* __restrict__ emb,
    bf16_t* __restrict__ Yt) {
    __shared__ float lds_emb[40];
    __shared__ float red[4][16][33];   // +1 pad: write bank = (4q+l15+r)%32, 2-way max
    __shared__ float reds[4][16];
    __shared__ bf16_t lds_p[4][16 * 32];
    const int b = blockIdx.x;
    const int h = b & 7;
    const int qt = b >> 3;
    const int t = threadIdx.x;
    if (t < 37) lds_emb[t] = (t < 36) ? emb[t * HH + h] : 0.0f;
    __syncthreads();

    const int wave = t >> 6, lane = t & 63;
    const int l15 = lane & 15, quad = lane >> 4;
    const int qg0 = qt * 16;
    const bf16_t* Qh = Qt + (size_t)h * NN * HD;
    const bf16_t* Kh = Kt + (size_t)h * NN * HD;
    const bf16_t* Vh = Vd + (size_t)h * HD * NN;

    const bf8v aq = *(const bf8v*)(Qh + (size_t)(qg0 + l15) * HD + quad * 8);

    int xi[4], yi[4];
#pragma unroll
    for (int r = 0; r < 4; r++) {
        int qi = qg0 + quad * 4 + r;
        xi[r] = qi / NYY;
        yi[r] = qi - xi[r] * NYY;
    }
    const int xi_lo = qg0 / NYY;            // wave-uniform (16 rows)
    const int xi_hi = (qg0 + 15) / NYY;

    f4v o0 = {0.f, 0.f, 0.f, 0.f}, o1 = {0.f, 0.f, 0.f, 0.f};
    const f4v z = {0.f, 0.f, 0.f, 0.f};
    float lsum[4] = {0.f, 0.f, 0.f, 0.f};
    bf16_t* plds = &lds_p[wave][0];

    const int k_begin = wave * (NN / 4), k_end = k_begin + NN / 4;
    for (int kb = k_begin; kb < k_end; kb += 32) {
        bf8v kf0 = *(const bf8v*)(Kh + (size_t)(kb + l15) * HD + quad * 8);
        bf8v kf1 = *(const bf8v*)(Kh + (size_t)(kb + 16 + l15) * HD + quad * 8);
        bf8v vf0 = *(const bf8v*)(Vh + (size_t)l15 * NN + kb + quad * 8);
        bf8v vf1 = *(const bf8v*)(Vh + (size_t)(16 + l15) * NN + kb + quad * 8);
        f4v s0 = mfma16(aq, kf0, z);
        f4v s1 = mfma16(aq, kf1, z);

        // Bias is 0 whenever |dx|>5: skip token math for chunks whose whole
        // x-range is out of window (wave-uniform branch, ~75% of chunks).
        const int xj_lo = kb / NYY;
        const int xj_hi = (kb + 31) / NYY;
        if (xj_lo > xi_hi + 5 || xj_hi + 5 < xi_lo) {
#pragma unroll
            for (int cb = 0; cb < 2; cb++) {
                const f4v& s = cb ? s1 : s0;
#pragma unroll
                for (int r = 0; r < 4; r++) {
                    float p = __expf(s[r]);
                    lsum[r] += p;
                    plds[(quad * 4 + r) * 32 + cb * 16 + l15] = (bf16_t)p;
                }
            }
        } else {
#pragma unroll
            for (int cb = 0; cb < 2; cb++) {
                const f4v& s = cb ? s1 : s0;
                int kj = kb + cb * 16 + l15;
                int xj = kj / NYY;
                int yj = kj - xj * NYY;
#pragma unroll
                for (int r = 0; r < 4; r++) {
                    int dx = xi[r] - xj; dx = dx < 0 ? -dx : dx;
                    int dy = yi[r] - yj; dy = dy < 0 ? -dy : dy;
                    int tok = (dx > 5 || dy > 5) ? 36 : dx * 6 + dy;
                    float p = __expf(s[r] + lds_emb[tok]);
                    lsum[r] += p;
                    plds[(quad * 4 + r) * 32 + cb * 16 + l15] = (bf16_t)p;
                }
            }
        }
        bf8v ap = *(const bf8v*)(plds + l15 * 32 + quad * 8);
        o0 = mfma16(ap, vf0, o0);
        o1 = mfma16(ap, vf1, o1);
    }

    // Stash per-wave partials in LDS.
#pragma unroll
    for (int r = 0; r < 4; r++) {
        float v = lsum[r];
#pragma unroll
        for (int m = 1; m < 16; m <<= 1) v += __shfl_xor(v, m, 64);
        const int row = quad * 4 + r;
        red[wave][row][l15] = o0[r];
        red[wave][row][16 + l15] = o1[r];
        if (l15 == 0) reds[wave][row] = v;
    }
    __syncthreads();

    // Combine across the 4 waves, normalize, write Yt.
#pragma unroll
    for (int e = t; e < 512; e += 256) {
        const int row = e >> 5;
        const int d = e & 31;
        float so = red[0][row][d] + red[1][row][d] + red[2][row][d] + red[3][row][d];
        float sl = reds[0][row] + reds[1][row] + reds[2][row] + reds[3][row];
        Yt[(size_t)(qg0 + row) * CC + h * HD + d] = (bf16_t)(so / sl);
    }
}

// ---------------------------------------------------------------------------
// Kernel 4: output projection (M=256, N=2304, K=256), bf16 W, fp32 out + bias.
// Block: 64 o x 32 n.
// ---------------------------------------------------------------------------
__global__ __launch_bounds__(256) void k_proj_out(
    const bf16_t* __restrict__ Wb, const float* __restrict__ bp,
    const bf16_t* __restrict__ Yt, float* __restrict__ out) {
    const bf16_t* W = Wb + (size_t)3 * 65536;
    const int n0 = blockIdx.x * 32;
    const int o0 = blockIdx.y * 64;
    const int lane = threadIdx.x & 63;
    const int wave = threadIdx.x >> 6;
    const int l15 = lane & 15;
    const int quad = lane >> 4;
    const int orow = o0 + wave * 16;

    f4v acc0 = {0.f, 0.f, 0.f, 0.f}, acc1 = {0.f, 0.f, 0.f, 0.f};
#pragma unroll
    for (int k0 = 0; k0 < CC; k0 += 32) {
        bf8v af = *(const bf8v*)(W + (size_t)(orow + l15) * CC + k0 + quad * 8);
        bf8v b0 = *(const bf8v*)(Yt + (size_t)(n0 + l15) * CC + k0 + quad * 8);
        bf8v b1 = *(const bf8v*)(Yt + (size_t)(n0 + 16 + l15) * CC + k0 + quad * 8);
        acc0 = mfma16(af, b0, acc0);
        acc1 = mfma16(af, b1, acc1);
    }

#pragma unroll
    for (int r = 0; r < 4; r++) {
        const int o = orow + quad * 4 + r;
        const float bo = bp[o];
        out[(size_t)o * NN + n0 + l15] = acc0[r] + bo;
        out[(size_t)o * NN + n0 + 16 + l15] = acc1[r] + bo;
    }
}

// ---------------------------------------------------------------------------
extern "C" void kernel_launch(void* const* d_in, const int* in_sizes, int n_in,
                              void* d_out, int out_size, void* d_ws, size_t ws_size,
                              hipStream_t stream) {
    const float* x   = (const float*)d_in[0];
    const float* Wq  = (const float*)d_in[1];
    const float* bq  = (const float*)d_in[2];
    const float* Wk  = (const float*)d_in[3];
    const float* bk  = (const float*)d_in[4];
    const float* Wv  = (const float*)d_in[5];
    const float* bv  = (const float*)d_in[6];
    const float* Wp  = (const float*)d_in[7];
    const float* bp  = (const float*)d_in[8];
    const float* emb = (const float*)d_in[9];
    // d_in[10] = tokens: recomputed analytically in-kernel, never read.
    float* out = (float*)d_out;

    bf16_t* xT = (bf16_t*)d_ws;              // NN*CC bf16
    bf16_t* Qt = xT + (size_t)NN * CC;       // (H, N, 32)
    bf16_t* Kt = Qt + (size_t)NN * CC;       // (H, N, 32)
    bf16_t* Vd = Kt + (size_t)NN * CC;       // (H, 32, N)
    bf16_t* Yt = Vd + (size_t)NN * CC;       // (N, 256)
    bf16_t* Wb = Yt + (size_t)NN * CC;       // 4 * 256*256 bf16

    hipLaunchKernelGGL(k_pre, dim3(288 + 128), dim3(256), 0, stream,
                       x, xT, Wq, Wk, Wv, Wp, Wb);
    hipLaunchKernelGGL(k_proj_qkv, dim3(72, 4, 3), dim3(256), 0, stream,
                       Wb, bq, bk, bv, xT, Qt, Kt, Vd);
    hipLaunchKernelGGL(k_attn, dim3(1152), dim3(256), 0, stream,
                       Qt, Kt, Vd, emb, Yt);
    hipLaunchKernelGGL(k_proj_out, dim3(72, 4), dim3(256), 0, stream, Wb, bp, Yt, out);
}

// Round 6
// 141.284 us; speedup vs baseline: 5.2596x; 1.0045x over previous
//
#include <hip/hip_runtime.h>

#define NN 2304
#define CC 256
#define HH 8
#define HD 32
#define NYY 48
#define SCALE 0.17677669529663687f

typedef __bf16 bf16_t;
typedef __bf16 bf8v __attribute__((ext_vector_type(8)));
typedef float f4v __attribute__((ext_vector_type(4)));

__device__ __forceinline__ f4v mfma16(bf8v a, bf8v b, f4v c) {
    return __builtin_amdgcn_mfma_f32_16x16x32_bf16(a, b, c, 0, 0, 0);
}

__device__ __forceinline__ bf8v cvt_w8(const float* p) {
    float4 a = *(const float4*)p;
    float4 c = *(const float4*)(p + 4);
    bf8v o;
    o[0] = (bf16_t)a.x; o[1] = (bf16_t)a.y; o[2] = (bf16_t)a.z; o[3] = (bf16_t)a.w;
    o[4] = (bf16_t)c.x; o[5] = (bf16_t)c.y; o[6] = (bf16_t)c.z; o[7] = (bf16_t)c.w;
    return o;
}

// ---------------------------------------------------------------------------
// Kernel 1: QKV projection GEMM (M=256 o, N=2304 n, K=256 c).
// No k_pre: W loaded f32 -> bf16 in-register; x staged per-block into LDS
// bf16 transposed [n][c] with XOR swizzle (cb ^= n&7 on 16B groups):
// write ~4-way conflict (one-time), ds_read_b128 ~2-way (free).
// Block: 64 o x 32 n (4 waves, each 16o x 32n, 2 accumulators).
//   Q -> Qt (H, N, 32) pre-scaled; K -> Kt (H, N, 32); V -> Vd (H, 32, N)
// ---------------------------------------------------------------------------
__global__ __launch_bounds__(256) void k_proj_qkv(
    const float* __restrict__ Wq, const float* __restrict__ Wk,
    const float* __restrict__ Wv,
    const float* __restrict__ bq, const float* __restrict__ bk,
    const float* __restrict__ bv,
    const float* __restrict__ x,
    bf16_t* __restrict__ Qt, bf16_t* __restrict__ Kt, bf16_t* __restrict__ Vd) {
    const int mat = blockIdx.z;
    const float* Wf = (mat == 0) ? Wq : (mat == 1) ? Wk : Wv;
    const float* bias = (mat == 0) ? bq : (mat == 1) ? bk : bv;
    const int n0 = blockIdx.x * 32;
    const int o0 = blockIdx.y * 64;
    const int t = threadIdx.x;
    const int lane = t & 63;
    const int wave = t >> 6;
    const int l15 = lane & 15;
    const int quad = lane >> 4;
    const int orow = o0 + wave * 16;

    // ---- stage x[0..256][n0..n0+32) -> xs[n][c] bf16, swizzled ----
    __shared__ bf16_t xs[32][256];
    {
        const int sn = t & 31;       // n within tile
        const int scg = t >> 5;      // 0..7
#pragma unroll
        for (int i = 0; i < 4; i++) {
            const int cb = i * 8 + scg;          // 16B group index, 0..31
            const int c0s = cb * 8;
            bf8v o;
#pragma unroll
            for (int j = 0; j < 8; j++) {
                o[j] = (bf16_t)x[(size_t)(c0s + j) * NN + n0 + sn];
            }
            *(bf8v*)(&xs[sn][(cb ^ (sn & 7)) * 8]) = o;
        }
    }
    __syncthreads();

    f4v acc0 = {0.f, 0.f, 0.f, 0.f}, acc1 = {0.f, 0.f, 0.f, 0.f};
#pragma unroll
    for (int k0 = 0; k0 < CC; k0 += 32) {
        bf8v af = cvt_w8(Wf + (size_t)(orow + l15) * CC + k0 + quad * 8);
        const int pcb = ((k0 >> 3) + quad);
        bf8v b0 = *(const bf8v*)(&xs[l15][(pcb ^ (l15 & 7)) * 8]);
        bf8v b1 = *(const bf8v*)(&xs[16 + l15][(pcb ^ (l15 & 7)) * 8]);
        acc0 = mfma16(af, b0, acc0);
        acc1 = mfma16(af, b1, acc1);
    }

#pragma unroll
    for (int r = 0; r < 4; r++) {
        const int o = orow + quad * 4 + r;
        const float bo = bias[o];
#pragma unroll
        for (int nb = 0; nb < 2; nb++) {
            const int n = n0 + nb * 16 + l15;
            float v = (nb ? acc1[r] : acc0[r]) + bo;
            if (mat == 2) {
                Vd[(size_t)o * NN + n] = (bf16_t)v;
            } else {
                int h = o >> 5, d = o & 31;
                bf16_t* dst = (mat == 0) ? Qt : Kt;
                float vv = (mat == 0) ? v * SCALE : v;
                dst[(size_t)h * NN * HD + (size_t)n * HD + d] = (bf16_t)vv;
            }
        }
    }
}

// ---------------------------------------------------------------------------
// Kernel 2: fused attention, split-K inside the block (no partial round-trip).
// Grid 1152 = 8 heads x 144 q-tiles of 16 rows. All 4 waves share the same
// 16 q-rows; wave w handles keys [w*576, (w+1)*576). Partials combined in
// LDS, normalized, written directly to Yt (N x 256) bf16.
// ---------------------------------------------------------------------------
__global__ __launch_bounds__(256, 4) void k_attn(
    const bf16_t* __restrict__ Qt, const bf16_t* __restrict__ Kt,
    const bf16_t* __restrict__ Vd, const float* __restrict__ emb,
    bf16_t* __restrict__ Yt) {
    __shared__ float lds_emb[40];
    __shared__ float red[4][16][33];   // +1 pad: 2-way max on write
    __shared__ float reds[4][16];
    __shared__ bf16_t lds_p[4][16 * 32];
    const int b = blockIdx.x;
    const int h = b & 7;
    const int qt = b >> 3;
    const int t = threadIdx.x;
    if (t < 37) lds_emb[t] = (t < 36) ? emb[t * HH + h] : 0.0f;
    __syncthreads();

    const int wave = t >> 6, lane = t & 63;
    const int l15 = lane & 15, quad = lane >> 4;
    const int qg0 = qt * 16;
    const bf16_t* Qh = Qt + (size_t)h * NN * HD;
    const bf16_t* Kh = Kt + (size_t)h * NN * HD;
    const bf16_t* Vh = Vd + (size_t)h * HD * NN;

    const bf8v aq = *(const bf8v*)(Qh + (size_t)(qg0 + l15) * HD + quad * 8);

    int xi[4], yi[4];
#pragma unroll
    for (int r = 0; r < 4; r++) {
        int qi = qg0 + quad * 4 + r;
        xi[r] = qi / NYY;
        yi[r] = qi - xi[r] * NYY;
    }
    const int xi_lo = qg0 / NYY;            // wave-uniform (16 rows)
    const int xi_hi = (qg0 + 15) / NYY;

    f4v o0 = {0.f, 0.f, 0.f, 0.f}, o1 = {0.f, 0.f, 0.f, 0.f};
    const f4v z = {0.f, 0.f, 0.f, 0.f};
    float lsum[4] = {0.f, 0.f, 0.f, 0.f};
    bf16_t* plds = &lds_p[wave][0];

    const int k_begin = wave * (NN / 4), k_end = k_begin + NN / 4;
    for (int kb = k_begin; kb < k_end; kb += 32) {
        bf8v kf0 = *(const bf8v*)(Kh + (size_t)(kb + l15) * HD + quad * 8);
        bf8v kf1 = *(const bf8v*)(Kh + (size_t)(kb + 16 + l15) * HD + quad * 8);
        bf8v vf0 = *(const bf8v*)(Vh + (size_t)l15 * NN + kb + quad * 8);
        bf8v vf1 = *(const bf8v*)(Vh + (size_t)(16 + l15) * NN + kb + quad * 8);
        f4v s0 = mfma16(aq, kf0, z);
        f4v s1 = mfma16(aq, kf1, z);

        // Bias is 0 whenever |dx|>5: skip token math for chunks whose whole
        // x-range is out of window (wave-uniform branch, ~75% of chunks).
        const int xj_lo = kb / NYY;
        const int xj_hi = (kb + 31) / NYY;
        if (xj_lo > xi_hi + 5 || xj_hi + 5 < xi_lo) {
#pragma unroll
            for (int cb = 0; cb < 2; cb++) {
                const f4v& s = cb ? s1 : s0;
#pragma unroll
                for (int r = 0; r < 4; r++) {
                    float p = __expf(s[r]);
                    lsum[r] += p;
                    plds[(quad * 4 + r) * 32 + cb * 16 + l15] = (bf16_t)p;
                }
            }
        } else {
#pragma unroll
            for (int cb = 0; cb < 2; cb++) {
                const f4v& s = cb ? s1 : s0;
                int kj = kb + cb * 16 + l15;
                int xj = kj / NYY;
                int yj = kj - xj * NYY;
#pragma unroll
                for (int r = 0; r < 4; r++) {
                    int dx = xi[r] - xj; dx = dx < 0 ? -dx : dx;
                    int dy = yi[r] - yj; dy = dy < 0 ? -dy : dy;
                    int tok = (dx > 5 || dy > 5) ? 36 : dx * 6 + dy;
                    float p = __expf(s[r] + lds_emb[tok]);
                    lsum[r] += p;
                    plds[(quad * 4 + r) * 32 + cb * 16 + l15] = (bf16_t)p;
                }
            }
        }
        bf8v ap = *(const bf8v*)(plds + l15 * 32 + quad * 8);
        o0 = mfma16(ap, vf0, o0);
        o1 = mfma16(ap, vf1, o1);
    }

    // Stash per-wave partials in LDS.
#pragma unroll
    for (int r = 0; r < 4; r++) {
        float v = lsum[r];
#pragma unroll
        for (int m = 1; m < 16; m <<= 1) v += __shfl_xor(v, m, 64);
        const int row = quad * 4 + r;
        red[wave][row][l15] = o0[r];
        red[wave][row][16 + l15] = o1[r];
        if (l15 == 0) reds[wave][row] = v;
    }
    __syncthreads();

    // Combine across the 4 waves, normalize, write Yt.
#pragma unroll
    for (int e = t; e < 512; e += 256) {
        const int row = e >> 5;
        const int d = e & 31;
        float so = red[0][row][d] + red[1][row][d] + red[2][row][d] + red[3][row][d];
        float sl = reds[0][row] + reds[1][row] + reds[2][row] + reds[3][row];
        Yt[(size_t)(qg0 + row) * CC + h * HD + d] = (bf16_t)(so / sl);
    }
}

// ---------------------------------------------------------------------------
// Kernel 3: output projection (M=256, N=2304, K=256).
// Wp loaded f32 -> bf16 in-register; Yt bf16 from k_attn. fp32 out + bias.
// Block: 64 o x 32 n.
// ---------------------------------------------------------------------------
__global__ __launch_bounds__(256) void k_proj_out(
    const float* __restrict__ Wp, const float* __restrict__ bp,
    const bf16_t* __restrict__ Yt, float* __restrict__ out) {
    const int n0 = blockIdx.x * 32;
    const int o0 = blockIdx.y * 64;
    const int lane = threadIdx.x & 63;
    const int wave = threadIdx.x >> 6;
    const int l15 = lane & 15;
    const int quad = lane >> 4;
    const int orow = o0 + wave * 16;

    f4v acc0 = {0.f, 0.f, 0.f, 0.f}, acc1 = {0.f, 0.f, 0.f, 0.f};
#pragma unroll
    for (int k0 = 0; k0 < CC; k0 += 32) {
        bf8v af = cvt_w8(Wp + (size_t)(orow + l15) * CC + k0 + quad * 8);
        bf8v b0 = *(const bf8v*)(Yt + (size_t)(n0 + l15) * CC + k0 + quad * 8);
        bf8v b1 = *(const bf8v*)(Yt + (size_t)(n0 + 16 + l15) * CC + k0 + quad * 8);
        acc0 = mfma16(af, b0, acc0);
        acc1 = mfma16(af, b1, acc1);
    }

#pragma unroll
    for (int r = 0; r < 4; r++) {
        const int o = orow + quad * 4 + r;
        const float bo = bp[o];
        out[(size_t)o * NN + n0 + l15] = acc0[r] + bo;
        out[(size_t)o * NN + n0 + 16 + l15] = acc1[r] + bo;
    }
}

// ---------------------------------------------------------------------------
extern "C" void kernel_launch(void* const* d_in, const int* in_sizes, int n_in,
                              void* d_out, int out_size, void* d_ws, size_t ws_size,
                              hipStream_t stream) {
    const float* x   = (const float*)d_in[0];
    const float* Wq  = (const float*)d_in[1];
    const float* bq  = (const float*)d_in[2];
    const float* Wk  = (const float*)d_in[3];
    const float* bk  = (const float*)d_in[4];
    const float* Wv  = (const float*)d_in[5];
    const float* bv  = (const float*)d_in[6];
    const float* Wp  = (const float*)d_in[7];
    const float* bp  = (const float*)d_in[8];
    const float* emb = (const float*)d_in[9];
    // d_in[10] = tokens: recomputed analytically in-kernel, never read.
    float* out = (float*)d_out;

    bf16_t* Qt = (bf16_t*)d_ws;              // (H, N, 32)
    bf16_t* Kt = Qt + (size_t)NN * CC;       // (H, N, 32)
    bf16_t* Vd = Kt + (size_t)NN * CC;       // (H, 32, N)
    bf16_t* Yt = Vd + (size_t)NN * CC;       // (N, 256)

    hipLaunchKernelGGL(k_proj_qkv, dim3(72, 4, 3), dim3(256), 0, stream,
                       Wq, Wk, Wv, bq, bk, bv, x, Qt, Kt, Vd);
    hipLaunchKernelGGL(k_attn, dim3(1152), dim3(256), 0, stream,
                       Qt, Kt, Vd, emb, Yt);
    hipLaunchKernelGGL(k_proj_out, dim3(72, 4), dim3(256), 0, stream, Wp, bp, Yt, out);
}